// Round 7
// baseline (251.382 us; speedup 1.0000x reference)
//
#include <hip/hip_runtime.h>
#include <hip/hip_bf16.h>
#include <stdint.h>

#define K_DIM 512
#define N_DIM 512
#define BM 64
#define CHUNK_K 64                       // fp32 k-columns per LDS chunk
#define CHUNK_FLOATS (BM * CHUNK_K)      // 4096 floats = 16 KiB
#define NBUF 3

typedef __bf16 bf16x8 __attribute__((ext_vector_type(8)));
typedef float floatx4 __attribute__((ext_vector_type(4)));

__device__ __forceinline__ bf16x8 cvt8(float4 a, float4 b) {
    bf16x8 r;
    r[0] = (__bf16)a.x; r[1] = (__bf16)a.y; r[2] = (__bf16)a.z; r[3] = (__bf16)a.w;
    r[4] = (__bf16)b.x; r[5] = (__bf16)b.y; r[6] = (__bf16)b.z; r[7] = (__bf16)b.w;
    return r;
}

// Pre-convert W [N,K] fp32 -> fragment-linear bf16:
// wf[((ntg*16+kcg)*64 + lane)*8 + j] = W[ntg*16+(lane&15)][kcg*32+(lane>>4)*8+j]
__global__ __launch_bounds__(512) void wconv_kernel(const float* __restrict__ w,
                                                    __bf16* __restrict__ wf) {
    int t = blockIdx.x * 512 + threadIdx.x;     // 0..32767
    int lane = t & 63, slot = t >> 6;           // slot = ntg*16+kcg
    int n = ((slot >> 4) << 4) + (lane & 15);
    int k = ((slot & 15) << 5) + ((lane >> 4) << 3);
    const float* src = w + (size_t)n * K_DIM + k;
    float4 f0 = *(const float4*)src;
    float4 f1 = *(const float4*)(src + 4);
    *(bf16x8*)(wf + (size_t)t * 8) = cvt8(f0, f1);
}

// stage one 64x64 fp32 chunk of x (16 KiB) with ONE global_load_lds per thread
// (1024 threads). LDS physical layout: row-major [64][64] fp32 (256 B/row);
// physical in-row byte p holds source in-row byte p ^ ((row&7)<<4).
// Linear LDS dest (wave-uniform base + lane*16) + inverse-swizzled global source.
__device__ __forceinline__ void stage_chunk(const float* __restrict__ x,
                                            int rowBase, int kBase,
                                            float* ldsBuf, int wid, int lane) {
    int row = wid * 4 + (lane >> 4);             // 0..63
    int srcByte = ((lane & 15) << 4) ^ ((row & 7) << 4);
    const float* g = x + (size_t)(rowBase + row) * K_DIM + kBase + (srcByte >> 2);
    float* l = ldsBuf + wid * 256;               // 1 KiB per wave, wave-uniform
    __builtin_amdgcn_global_load_lds(
        (const __attribute__((address_space(1))) void*)g,
        (__attribute__((address_space(3))) void*)l, 16, 0, 0);
}

// read A fragment from swizzled fp32 chunk -> bf16x8 (each 16B half at its OWN
// swizzled address — round-4 lesson).
__device__ __forceinline__ bf16x8 read_afrag(const float* ldsBuf, int mg, int rt,
                                             int kcl, int lane) {
    int row = mg * 32 + rt * 16 + (lane & 15);
    int sw = (row & 7) << 4;
    int b0 = kcl * 128 + ((lane >> 4) << 5);     // source byte-in-row
    const char* rb = (const char*)(ldsBuf + row * CHUNK_K);
    float4 fa = *(const float4*)(rb + (b0 ^ sw));
    float4 fb = *(const float4*)(rb + ((b0 + 16) ^ sw));
    return cvt8(fa, fb);
}

// load W fragments for chunk c into registers (8 or 16 vm ops)
template <bool USE_WF>
__device__ __forceinline__ void load_wfrag(bf16x8 (&dst)[4][2], int c,
                                           const __bf16* __restrict__ wf,
                                           const float* __restrict__ w,
                                           int ng, int lane) {
    int kk = c & 7;
    #pragma unroll
    for (int nt = 0; nt < 4; ++nt) {
        int ntg = ng * 4 + nt;
        #pragma unroll
        for (int kcl = 0; kcl < 2; ++kcl) {
            int kcg = kk * 2 + kcl;
            if (USE_WF) {
                dst[nt][kcl] = *(const bf16x8*)(wf + (size_t)(((ntg << 4) + kcg) * 64 + lane) * 8);
            } else {
                int n = (ntg << 4) + (lane & 15);
                const float* s = w + (size_t)n * K_DIM + (kcg << 5) + ((lane >> 4) << 3);
                dst[nt][kcl] = cvt8(*(const float4*)s, *(const float4*)(s + 4));
            }
        }
    }
}

// One chunk iteration. vm-queue discipline (issue order pinned by sched_barrier +
// memory-clobber asm):  wf(c+1) THEN stage(c+2); wait vmcnt(WOPS+2) retires exactly
// {stage(c), wf(c)} and keeps {stage(c+1), wf(c+1), stage(c+2)} in flight.
// Iters right after an epilogue use vmcnt(WOPS+12) (epilogue's 10-14 vm ops sit
// between wf(c) and wf(c+1) in the queue; value is safe for 10..14 actual ops).
template <bool USE_WF>
__device__ __forceinline__ void chunk_body(
    int c, int nChunks, int ibR, int tile0,
    const float* __restrict__ x, const float* __restrict__ xscale,
    const __bf16* __restrict__ wf, const float* __restrict__ w,
    const float* __restrict__ wscale, float* __restrict__ out,
    float* lds, bf16x8 (&wfU)[4][2], bf16x8 (&wfF)[4][2], floatx4 (&acc)[2][4],
    int wid, int lane, int mg, int ng)
{
    constexpr int WOPS = USE_WF ? 8 : 16;
    const int laneR = lane & 15;

    // [1] all waves done reading buf[(c-1)%3] -> safe to overwrite later
    asm volatile("s_waitcnt lgkmcnt(0)\n\ts_barrier" ::: "memory");

    // [2] prefetch W fragments for chunk c+1 (into the OTHER register set)
    {
        int cn = (c + 1 < nChunks) ? c + 1 : nChunks - 1;
        load_wfrag<USE_WF>(wfF, cn, wf, w, ng, lane);
    }
    __builtin_amdgcn_sched_barrier(0);

    // [3] issue stage(c+2) into buf[(c+2)%3]
    {
        int cs = (c + 2 < nChunks) ? c + 2 : nChunks - 1;
        int ibS = ibR + 2; if (ibS >= NBUF) ibS -= NBUF;
        stage_chunk(x, (tile0 + (cs >> 3)) * BM, (cs & 7) * CHUNK_K,
                    lds + ibS * CHUNK_FLOATS, wid, lane);
    }
    __builtin_amdgcn_sched_barrier(0);

    // [4] retire {stage(c), wf(c)}; keep newer ops in flight
    if (c > 0 && (c & 7) == 0)
        asm volatile("s_waitcnt vmcnt(%0)\n\ts_barrier" :: "i"(WOPS + 12) : "memory");
    else
        asm volatile("s_waitcnt vmcnt(%0)\n\ts_barrier" :: "i"(WOPS + 2) : "memory");

    // [5] new tile -> reset accumulators
    if ((c & 7) == 0) {
        #pragma unroll
        for (int i = 0; i < 2; ++i)
            #pragma unroll
            for (int j = 0; j < 4; ++j) acc[i][j] = (floatx4)0.f;
    }

    // [6] compute: 2 k32-steps, zero vm ops
    const float* cb = lds + ibR * CHUNK_FLOATS;
    #pragma unroll
    for (int kcl = 0; kcl < 2; ++kcl) {
        bf16x8 ax[2];
        #pragma unroll
        for (int rt = 0; rt < 2; ++rt)
            ax[rt] = read_afrag(cb, mg, rt, kcl, lane);
        #pragma unroll
        for (int nt = 0; nt < 4; ++nt)
            #pragma unroll
            for (int rt = 0; rt < 2; ++rt)
                acc[rt][nt] = __builtin_amdgcn_mfma_f32_16x16x32_bf16(
                    wfU[nt][kcl], ax[rt], acc[rt][nt], 0, 0, 0);
    }

    // [7] tile finished -> dequant + fp32 float4 stores (vm ops drained by the
    //     elevated vmcnt on the next iteration)
    if ((c & 7) == 7) {
        const int rowb = (tile0 + (c >> 3)) * BM;
        #pragma unroll
        for (int rt = 0; rt < 2; ++rt) {
            int m = rowb + mg * 32 + rt * 16 + laneR;
            float xs = xscale[m];
            #pragma unroll
            for (int nt = 0; nt < 4; ++nt) {
                int nb = ng * 64 + (nt << 4) + ((lane >> 4) << 2);
                float4 wsc = *(const float4*)(wscale + nb);
                floatx4 a = acc[rt][nt];
                float4 o;
                o.x = a[0] * xs * wsc.x;
                o.y = a[1] * xs * wsc.y;
                o.z = a[2] * xs * wsc.z;
                o.w = a[3] * xs * wsc.w;
                *(float4*)(out + (size_t)m * N_DIM + nb) = o;
            }
        }
    }
}

// Persistent pipelined GEMM: 1024 threads = 16 waves (2M x 8N), wave tile 32x64.
template <bool USE_WF>
__global__ __launch_bounds__(1024) void gemm_kernel(
    const float* __restrict__ x, const float* __restrict__ xscale,
    const __bf16* __restrict__ wf, const float* __restrict__ w,
    const float* __restrict__ wscale, float* __restrict__ out,
    int ntiles, int tilesPerBlock)
{
    __shared__ __align__(16) float lds[NBUF * CHUNK_FLOATS];   // 48 KiB, 3 bufs
    const int t = threadIdx.x;
    const int lane = t & 63;
    const int wid = t >> 6;                      // 0..15
    const int mg = wid >> 3;                     // 0..1
    const int ng = wid & 7;                      // 0..7

    const int tile0 = blockIdx.x * tilesPerBlock;
    if (tile0 >= ntiles) return;
    const int tileEnd = (tile0 + tilesPerBlock < ntiles) ? (tile0 + tilesPerBlock) : ntiles;
    const int nChunks = (tileEnd - tile0) * 8;   // multiple of 8 (so even)

    floatx4 acc[2][4];
    bf16x8 wfrA[4][2], wfrB[4][2];

    // prologue — queue order matters: stage(0), wf(0), stage(1)
    stage_chunk(x, tile0 * BM, 0, lds, wid, lane);
    load_wfrag<USE_WF>(wfrA, 0, wf, w, ng, lane);
    __builtin_amdgcn_sched_barrier(0);
    stage_chunk(x, tile0 * BM, CHUNK_K, lds + CHUNK_FLOATS, wid, lane);
    __builtin_amdgcn_sched_barrier(0);

    int ibR = 0;
    for (int c = 0; c < nChunks; c += 2) {
        chunk_body<USE_WF>(c, nChunks, ibR, tile0, x, xscale, wf, w, wscale, out,
                           lds, wfrA, wfrB, acc, wid, lane, mg, ng);
        ibR = (ibR + 1 < NBUF) ? ibR + 1 : 0;
        chunk_body<USE_WF>(c + 1, nChunks, ibR, tile0, x, xscale, wf, w, wscale, out,
                           lds, wfrB, wfrA, acc, wid, lane, mg, ng);
        ibR = (ibR + 1 < NBUF) ? ibR + 1 : 0;
    }
}

extern "C" void kernel_launch(void* const* d_in, const int* in_sizes, int n_in,
                              void* d_out, int out_size, void* d_ws, size_t ws_size,
                              hipStream_t stream) {
    const float* x      = (const float*)d_in[0];
    const float* xscale = (const float*)d_in[1];
    const float* w      = (const float*)d_in[2];
    const float* wscale = (const float*)d_in[3];
    float* out          = (float*)d_out;

    const int M = in_sizes[0] / K_DIM;            // 131072
    const int ntiles = M / BM;                    // 2048
    const int nblocks = (ntiles < 256) ? ntiles : 256;
    const int tpb = (ntiles + nblocks - 1) / nblocks;   // 8

    if (ws_size >= (size_t)(N_DIM * K_DIM * sizeof(unsigned short))) {
        __bf16* wfp = (__bf16*)d_ws;
        wconv_kernel<<<dim3(64), dim3(512), 0, stream>>>(w, wfp);
        gemm_kernel<true><<<dim3(nblocks), dim3(1024), 0, stream>>>(
            x, xscale, wfp, w, wscale, out, ntiles, tpb);
    } else {
        gemm_kernel<false><<<dim3(nblocks), dim3(1024), 0, stream>>>(
            x, xscale, nullptr, w, wscale, out, ntiles, tpb);
    }
}

// Round 8
// 198.425 us; speedup vs baseline: 1.2669x; 1.2669x over previous
//
#include <hip/hip_runtime.h>
#include <hip/hip_bf16.h>
#include <stdint.h>

#define K_DIM 512
#define N_DIM 512
#define BM 64
#define PHASE_K 128                          // fp32 k-columns per LDS phase
#define PHASE_FLOATS (BM * PHASE_K)          // 8192 floats = 32 KiB

typedef __bf16 bf16x8 __attribute__((ext_vector_type(8)));
typedef float floatx4 __attribute__((ext_vector_type(4)));

__device__ __forceinline__ bf16x8 cvt8(float4 a, float4 b) {
    bf16x8 r;
    r[0] = (__bf16)a.x; r[1] = (__bf16)a.y; r[2] = (__bf16)a.z; r[3] = (__bf16)a.w;
    r[4] = (__bf16)b.x; r[5] = (__bf16)b.y; r[6] = (__bf16)b.z; r[7] = (__bf16)b.w;
    return r;
}

// Pre-convert W [N,K] fp32 -> fragment-linear bf16:
// wf[((ntg*16+kcg)*64 + lane)*8 + j] = W[ntg*16+(lane&15)][kcg*32+(lane>>4)*8+j]
__global__ __launch_bounds__(512) void wconv_kernel(const float* __restrict__ w,
                                                    __bf16* __restrict__ wf) {
    int t = blockIdx.x * 512 + threadIdx.x;     // 0..32767
    int lane = t & 63, slot = t >> 6;           // slot = ntg*16+kcg
    int n = ((slot >> 4) << 4) + (lane & 15);
    int k = ((slot & 15) << 5) + ((lane >> 4) << 3);
    const float* src = w + (size_t)n * K_DIM + k;
    float4 f0 = *(const float4*)src;
    float4 f1 = *(const float4*)(src + 4);
    *(bf16x8*)(wf + (size_t)t * 8) = cvt8(f0, f1);
}

// Stage one 64x128 fp32 slab of x into ldsBuf via global_load_lds, 4 ops/thread
// (512 threads). LDS physical layout: row-major [64][128] fp32 (512 B/row);
// physical in-row byte p holds source in-row byte p ^ ((row&7)<<4). Linear LDS
// dest (wave-uniform base + lane*16) + inverse-swizzled per-lane GLOBAL source
// (rule #21; verified in round 5).
__device__ __forceinline__ void stage_phase(const float* __restrict__ x,
                                            int rowBase, int kBase,
                                            float* ldsBuf, int wid, int lane) {
    #pragma unroll
    for (int i = 0; i < 4; ++i) {
        int sl = i * 8 + wid;                    // 0..31, wave-uniform
        int row = sl * 2 + (lane >> 5);          // 0..63
        int srcByte = ((lane & 31) * 16) ^ ((row & 7) << 4);
        const float* g = x + (size_t)(rowBase + row) * K_DIM + kBase + (srcByte >> 2);
        float* l = ldsBuf + sl * 256;            // 1 KiB per sl, wave-uniform
        __builtin_amdgcn_global_load_lds(
            (const __attribute__((address_space(1))) void*)g,
            (__attribute__((address_space(3))) void*)l, 16, 0, 0);
    }
}

// Read A fragment (rt, kcl) from the swizzled fp32 slab -> bf16x8.
// Each 16B half fetched at its OWN swizzled address (round-4 lesson; round-5 verified).
__device__ __forceinline__ bf16x8 read_afrag(const float* ldsBuf, int rt, int kcl, int lane) {
    int row = rt * 16 + (lane & 15);
    int sw = (row & 7) << 4;
    int b0 = kcl * 128 + ((lane >> 4) << 5);     // source byte-in-row
    const char* rb = (const char*)(ldsBuf + row * PHASE_K);
    float4 fa = *(const float4*)(rb + (b0 ^ sw));
    float4 fb = *(const float4*)(rb + ((b0 + 16) ^ sw));
    return cvt8(fa, fb);
}

// One output tile (64 rows x 512 cols) per block. 8 waves, wave tile 64x64.
// K split into 4 phases of 128; LDS double-buffered (2 x 32 KiB); stage(p+1)
// issued right after the phase-top __syncthreads so it overlaps compute(p) and
// drains at the next sync (compiler's vmcnt(0)-before-barrier). 2 blocks/CU
// provide cross-block overlap for the residual latency (m114 mechanism).
template <bool USE_WF>
__global__ __launch_bounds__(512, 4) void gemm_kernel(
    const float* __restrict__ x, const float* __restrict__ xscale,
    const __bf16* __restrict__ wf, const float* __restrict__ w,
    const float* __restrict__ wscale, float* __restrict__ out)
{
    __shared__ __align__(16) float lds[2 * PHASE_FLOATS];   // 64 KiB
    const int t = threadIdx.x;
    const int lane = t & 63;
    const int wid = t >> 6;                      // 0..7
    const int laneR = lane & 15;
    const int colb = wid * 64;
    const int rowb = blockIdx.x * BM;

    floatx4 acc[4][4];
    #pragma unroll
    for (int i = 0; i < 4; ++i)
        #pragma unroll
        for (int j = 0; j < 4; ++j) acc[i][j] = (floatx4)0.f;

    // prologue: issue phase-0 stage
    stage_phase(x, rowb, 0, lds, wid, lane);

    #pragma unroll
    for (int p = 0; p < 4; ++p) {
        // drains all outstanding vm ops per wave (incl. stage(p)) then barriers:
        // after this, buf[p&1] fully staged and prior readers of buf[(p+1)&1] done.
        __syncthreads();

        // issue next phase's stage into the other buffer; it flies during compute(p)
        if (p < 3)
            stage_phase(x, rowb, (p + 1) * PHASE_K, &lds[((p + 1) & 1) * PHASE_FLOATS],
                        wid, lane);

        const float* cb = &lds[(p & 1) * PHASE_FLOATS];
        #pragma unroll
        for (int kcl = 0; kcl < 4; ++kcl) {
            const int kcg = p * 4 + kcl;         // global k32 index 0..15
            bf16x8 ax[4];
            #pragma unroll
            for (int rt = 0; rt < 4; ++rt)
                ax[rt] = read_afrag(cb, rt, kcl, lane);
            #pragma unroll
            for (int nt = 0; nt < 4; ++nt) {
                bf16x8 bw;
                if (USE_WF) {
                    int ntg = (wid << 2) + nt;
                    bw = *(const bf16x8*)(wf + (size_t)(((ntg << 4) + kcg) * 64 + lane) * 8);
                } else {
                    int n = colb + (nt << 4) + laneR;
                    const float* src = w + (size_t)n * K_DIM + (kcg << 5) + ((lane >> 4) << 3);
                    bw = cvt8(*(const float4*)src, *(const float4*)(src + 4));
                }
                // D = W_frag x X_frag -> D holds out^T: row -> n, col -> m
                #pragma unroll
                for (int rt = 0; rt < 4; ++rt)
                    acc[rt][nt] = __builtin_amdgcn_mfma_f32_16x16x32_bf16(
                        bw, ax[rt], acc[rt][nt], 0, 0, 0);
            }
        }
    }

    // epilogue: dequant + fp32 float4 stores (4 consecutive n per lane)
    #pragma unroll
    for (int rt = 0; rt < 4; ++rt) {
        int m = rowb + rt * 16 + laneR;
        float xs = xscale[m];
        #pragma unroll
        for (int nt = 0; nt < 4; ++nt) {
            int nb = colb + (nt << 4) + ((lane >> 4) << 2);
            float4 wsc = *(const float4*)(wscale + nb);
            floatx4 a = acc[rt][nt];
            float4 o;
            o.x = a[0] * xs * wsc.x;
            o.y = a[1] * xs * wsc.y;
            o.z = a[2] * xs * wsc.z;
            o.w = a[3] * xs * wsc.w;
            *(float4*)(out + (size_t)m * N_DIM + nb) = o;
        }
    }
}

extern "C" void kernel_launch(void* const* d_in, const int* in_sizes, int n_in,
                              void* d_out, int out_size, void* d_ws, size_t ws_size,
                              hipStream_t stream) {
    const float* x      = (const float*)d_in[0];
    const float* xscale = (const float*)d_in[1];
    const float* w      = (const float*)d_in[2];
    const float* wscale = (const float*)d_in[3];
    float* out          = (float*)d_out;

    const int M = in_sizes[0] / K_DIM;            // 131072
    const int grid = M / BM;                      // 2048

    if (ws_size >= (size_t)(N_DIM * K_DIM * sizeof(unsigned short))) {
        __bf16* wfp = (__bf16*)d_ws;
        wconv_kernel<<<dim3(64), dim3(512), 0, stream>>>(w, wfp);
        gemm_kernel<true><<<dim3(grid), dim3(512), 0, stream>>>(
            x, xscale, wfp, w, wscale, out);
    } else {
        gemm_kernel<false><<<dim3(grid), dim3(512), 0, stream>>>(
            x, xscale, nullptr, w, wscale, out);
    }
}